// Round 1
// baseline (352.032 us; speedup 1.0000x reference)
//
#include <hip/hip_runtime.h>
#include <hip/hip_bf16.h>

// HopfieldTSP: reference iterates x = sign(w @ x) 1000 times, with
// w = -adj off-diagonal, w_ii = 2*rowsum_i.
//
// Math: for any x in {±1}^n, (w@x)_i = (2*rowsum_i + adj_ii)*x_i - (adj@x)_i,
// and since adj >= 0, |(adj@x)_i| <= rowsum_i < 2*rowsum_i. So every ±1
// vector is a fixed point: sign(w@x) = x. Hence x_1000 = x_1 = sign(w @ x0).
// The entire problem is ONE fused matvec + rowsum pass (256 MiB HBM read).

#define N_CITIES 8192
#define WAVES_PER_BLOCK 4   // 256 threads, 4 rows per block

__global__ __launch_bounds__(64 * WAVES_PER_BLOCK) void
hopfield_onestep_kernel(const float* __restrict__ adj,
                        const float* __restrict__ x,
                        float* __restrict__ out) {
    const int wave = threadIdx.x >> 6;
    const int lane = threadIdx.x & 63;
    const int row  = blockIdx.x * WAVES_PER_BLOCK + wave;
    if (row >= N_CITIES) return;

    const float4* __restrict__ arow =
        (const float4*)(adj + (size_t)row * N_CITIES);
    const float4* __restrict__ xv4 = (const float4*)x;

    float dot  = 0.0f;   // sum_j adj[row][j] * x[j]
    float rsum = 0.0f;   // sum_j adj[row][j]

    // 8192 floats = 2048 float4; 64 lanes -> 32 iterations/lane.
    #pragma unroll 4
    for (int c = lane; c < (N_CITIES / 4); c += 64) {
        float4 a  = arow[c];
        float4 xv = xv4[c];           // 32 KB vector: L1/L2 resident
        dot  += a.x * xv.x + a.y * xv.y + a.z * xv.z + a.w * xv.w;
        rsum += a.x + a.y + a.z + a.w;
    }

    // wave64 butterfly reduction
    #pragma unroll
    for (int off = 32; off > 0; off >>= 1) {
        dot  += __shfl_down(dot,  off, 64);
        rsum += __shfl_down(rsum, off, 64);
    }

    if (lane == 0) {
        float xi  = x[row];
        float aii = adj[(size_t)row * N_CITIES + row];
        float y   = (aii + 2.0f * rsum) * xi - dot;
        out[row]  = (y > 0.0f) ? 1.0f : ((y < 0.0f) ? -1.0f : 0.0f);
    }
}

extern "C" void kernel_launch(void* const* d_in, const int* in_sizes, int n_in,
                              void* d_out, int out_size, void* d_ws, size_t ws_size,
                              hipStream_t stream) {
    const float* adj = (const float*)d_in[0];
    const float* x   = (const float*)d_in[1];
    float* out       = (float*)d_out;

    const int rows_per_block = WAVES_PER_BLOCK;
    const int grid = (N_CITIES + rows_per_block - 1) / rows_per_block;  // 2048
    hopfield_onestep_kernel<<<grid, 64 * WAVES_PER_BLOCK, 0, stream>>>(adj, x, out);
}